// Round 1
// baseline (281.361 us; speedup 1.0000x reference)
//
#include <hip/hip_runtime.h>
#include <math.h>

#define B_DIM 4096
#define T_DIM 4096

constexpr float GAMMA_F = 0.99f;
constexpr float CLIP_V  = 5.0f;

// constexpr-folded gamma powers
constexpr float G2    = GAMMA_F * GAMMA_F; // g^2
constexpr float G4    = G2 * G2;           // g^4
constexpr float G8    = G4 * G4;           // g^8
constexpr float Q1    = G8 * G8;           // g^16
constexpr float Q2    = Q1 * Q1;           // g^32
constexpr float Q4    = Q2 * Q2;           // g^64
constexpr float Q8    = Q4 * Q4;           // g^128
constexpr float Q16   = Q8 * Q8;           // g^256
constexpr float Q32   = Q16 * Q16;         // g^512
constexpr float G1024 = Q32 * Q32;         // g^1024

// g^(4*e), e in [0,63], binary exponentiation (deterministic)
__device__ __forceinline__ float pow_g4(int e) {
    float f = 1.0f;
    if (e & 1)  f *= G4;
    if (e & 2)  f *= G8;
    if (e & 4)  f *= Q1;
    if (e & 8)  f *= Q2;
    if (e & 16) f *= Q4;
    if (e & 32) f *= Q8;
    return f;
}

// fast log_sigmoid: arg of log is in [1,2] -> v_log_f32 precision is plenty
__device__ __forceinline__ float lsig(float x) {
    return fminf(x, 0.0f) - __logf(1.0f + __expf(-fabsf(x)));
}

// ---------------------------------------------------------------------------
// K1: per-row reverse discounted scan. One block (256 thr) per row.
// COALESCED ownership (R2): wave wv owns row segment [wv*1024, wv*1024+1024).
// That segment is split into 4 j-blocks of 256 elements; lane l owns the
// 4-element granule at j*256 + l*4. Every float4 load/store is lane-stride
// 16 B -> each cache line touched exactly once (previous 64 B/lane layout
// touched 4x the lines via the L1, which was the throughput limit: VALUBusy
// 17%, HBM 26%, nothing saturated).
// Scan: granule Horner -> per-j wave Kogge-Stone suffix scan (factor g^4)
// -> cross-j Horner (g^256) -> cross-wave Horner (g^1024) -> per-granule
// carry sn[j] + g^(4(63-l)) * U[j+1] -> coalesced float4 stores.
// ---------------------------------------------------------------------------
__global__ __launch_bounds__(256) void k_scan(const float4* __restrict__ logits,
                                              const float4* __restrict__ weight,
                                              float4* __restrict__ cum) {
    __shared__ float waveS[4];
    const int row = blockIdx.x;
    const int tid = threadIdx.x;
    const int wv = tid >> 6, ln = tid & 63;
    const size_t rb  = (size_t)row * (T_DIM / 4);
    const int    seg = wv * 256 + ln;          // float4 index of j=0 granule

    // coalesced loads, wr = weight * log_sigmoid(logits)
    float wr[16];
    #pragma unroll
    for (int j = 0; j < 4; ++j) {
        float4 x4 = logits[rb + seg + j * 64];
        float4 w4 = weight[rb + seg + j * 64];
        wr[4 * j + 0] = w4.x * lsig(x4.x);
        wr[4 * j + 1] = w4.y * lsig(x4.y);
        wr[4 * j + 2] = w4.z * lsig(x4.z);
        wr[4 * j + 3] = w4.w * lsig(x4.w);
    }

    // per-j: granule value, wave suffix scan (granule spacing 4), next-lane
    // suffix sn[j], block total t[j]
    float t[4], sn[4];
    const float F4[6] = {G4, G8, Q1, Q2, Q4, Q8};   // g^(4*2^k)
    #pragma unroll
    for (int j = 0; j < 4; ++j) {
        float V = 0.0f;
        #pragma unroll
        for (int i = 3; i >= 0; --i) V = fmaf(GAMMA_F, V, wr[4 * j + i]);
        float s = V;
        #pragma unroll
        for (int k = 0; k < 6; ++k) {
            int off = 1 << k;
            float u = __shfl_down(s, off, 64);
            if (ln + off < 64) s = fmaf(F4[k], u, s);
        }
        float nx = __shfl_down(s, 1, 64);
        sn[j] = (ln == 63) ? 0.0f : nx;        // suffix starting at next granule
        t[j]  = __shfl(s, 0, 64);              // block-j total (ref at block start)
    }

    // wave total (blocks 0..3, ref at wave start) -> LDS
    float W = fmaf(Q16, fmaf(Q16, fmaf(Q16, t[3], t[2]), t[1]), t[0]);
    if (ln == 0) waveS[wv] = W;
    __syncthreads();

    // inclusive suffix at start of next wave (Horner over g^1024)
    float Anext = 0.0f;
    for (int w2 = 3; w2 > wv; --w2) Anext = fmaf(G1024, Anext, waveS[w2]);

    // U[j] = suffix total starting at block j's start (j=1..3), U[4] = Anext
    float U[5];
    U[4] = Anext;
    #pragma unroll
    for (int j = 3; j >= 1; --j) U[j] = fmaf(Q16, U[j + 1], t[j]);

    // distance from granule end to next block start = 4*(63-ln)
    const float fac = pow_g4(63 - ln);

    // final per-granule scan + coalesced float4 stores
    #pragma unroll
    for (int j = 0; j < 4; ++j) {
        float carry = fmaf(fac, U[j + 1], sn[j]);
        float4 o4;
        o4.w = carry = fmaf(GAMMA_F, carry, wr[4 * j + 3]);
        o4.z = carry = fmaf(GAMMA_F, carry, wr[4 * j + 2]);
        o4.y = carry = fmaf(GAMMA_F, carry, wr[4 * j + 1]);
        o4.x = carry = fmaf(GAMMA_F, carry, wr[4 * j + 0]);
        cum[rb + seg + j * 64] = o4;
    }
}

// zero colsum (ws is re-poisoned to 0xAA before every call)
__global__ __launch_bounds__(256) void k_zero(float* __restrict__ p) {
    p[blockIdx.x * 256 + threadIdx.x] = 0.0f;
}

// ---------------------------------------------------------------------------
// K2: column sums of (cum - baselines) via per-block partial + one atomic
// per column per block. grid (T/256, 128): 2048 blocks (8/CU), 32 rows each.
// ---------------------------------------------------------------------------
__global__ __launch_bounds__(256) void k_colsum(const float* __restrict__ cum,
                                                const float* __restrict__ baselines,
                                                float* __restrict__ colsum) {
    const int t = blockIdx.x * 256 + threadIdx.x;
    size_t p = (size_t)(blockIdx.y * 32) * T_DIM + t;
    float s0 = 0.0f, s1 = 0.0f, s2 = 0.0f, s3 = 0.0f;
    #pragma unroll
    for (int r = 0; r < 32; r += 4) {
        s0 += cum[p] - baselines[p];               p += T_DIM;
        s1 += cum[p] - baselines[p];               p += T_DIM;
        s2 += cum[p] - baselines[p];               p += T_DIM;
        s3 += cum[p] - baselines[p];               p += T_DIM;
    }
    atomicAdd(&colsum[t], (s0 + s1) + (s2 + s3));
}

// ---------------------------------------------------------------------------
// K3: obj[row] = sum_t clip(cum - base - colsum/B) * log_probs, float4 loads
// ---------------------------------------------------------------------------
__global__ __launch_bounds__(256) void k_obj(const float4* __restrict__ cum,
                                             const float4* __restrict__ baselines,
                                             const float4* __restrict__ logp,
                                             const float4* __restrict__ colsum,
                                             float* __restrict__ obj) {
    constexpr float invB = 1.0f / B_DIM;
    const int row = blockIdx.x, tid = threadIdx.x;
    const size_t base4 = (size_t)row * (T_DIM / 4);
    float acc = 0.0f;
    #pragma unroll
    for (int j = 0; j < 4; ++j) {
        int t4 = j * 256 + tid;
        float4 c = cum[base4 + t4];
        float4 b = baselines[base4 + t4];
        float4 l = logp[base4 + t4];
        float4 m = colsum[t4];
        float a0 = fminf(fmaxf(c.x - b.x - m.x * invB, -CLIP_V), CLIP_V);
        float a1 = fminf(fmaxf(c.y - b.y - m.y * invB, -CLIP_V), CLIP_V);
        float a2 = fminf(fmaxf(c.z - b.z - m.z * invB, -CLIP_V), CLIP_V);
        float a3 = fminf(fmaxf(c.w - b.w - m.w * invB, -CLIP_V), CLIP_V);
        acc = fmaf(a0, l.x, acc);
        acc = fmaf(a1, l.y, acc);
        acc = fmaf(a2, l.z, acc);
        acc = fmaf(a3, l.w, acc);
    }
    #pragma unroll
    for (int off = 32; off > 0; off >>= 1) acc += __shfl_down(acc, off, 64);
    __shared__ float ws4[4];
    if ((tid & 63) == 0) ws4[tid >> 6] = acc;
    __syncthreads();
    if (tid == 0) obj[row] = (ws4[0] + ws4[1]) + (ws4[2] + ws4[3]);
}

extern "C" void kernel_launch(void* const* d_in, const int* in_sizes, int n_in,
                              void* d_out, int out_size, void* d_ws, size_t ws_size,
                              hipStream_t stream) {
    const float* log_probs = (const float*)d_in[0];
    const float* logits    = (const float*)d_in[1];
    const float* weight    = (const float*)d_in[2];
    const float* baselines = (const float*)d_in[3];

    float* obj = (float*)d_out;       // [B]
    float* cum = obj + B_DIM;         // [B*T]
    float* colsum = (float*)d_ws;     // [T] (16 KB of ws)

    k_zero  <<<T_DIM / 256, 256, 0, stream>>>(colsum);
    k_scan  <<<B_DIM, 256, 0, stream>>>((const float4*)logits, (const float4*)weight,
                                        (float4*)cum);
    k_colsum<<<dim3(T_DIM / 256, 128), 256, 0, stream>>>(cum, baselines, colsum);
    k_obj   <<<B_DIM, 256, 0, stream>>>((const float4*)cum, (const float4*)baselines,
                                        (const float4*)log_probs, (const float4*)colsum, obj);
}